// Round 7
// baseline (445.921 us; speedup 1.0000x reference)
//
#include <hip/hip_runtime.h>

#define NB 2
#define NS 4096
#define ND 1152
#define NH 16
#define HD 72
#define HP 80            // q/k padded head dim (cols 72..79 zero)
#define VP 96            // v_t rows (72=ones, 73..95 zero)
// 72^-0.5 * log2(e): attention computed in exp2 domain
#define QSCALE (0.11785113019775793f * 1.4426950408889634f)

typedef float f32x4 __attribute__((ext_vector_type(4)));
typedef float f32x16 __attribute__((ext_vector_type(16)));
typedef __bf16 bf16x8 __attribute__((ext_vector_type(8)));
typedef unsigned short u16x8 __attribute__((ext_vector_type(8)));
typedef unsigned short u16x4 __attribute__((ext_vector_type(4)));
typedef unsigned int u32x4 __attribute__((ext_vector_type(4)));

__device__ __forceinline__ unsigned short f2bf(float f) {
  return __builtin_bit_cast(unsigned short, (__bf16)f);  // v_cvt RNE
}
__device__ __forceinline__ bf16x8 asbf(u16x8 u) {
  return __builtin_bit_cast(bf16x8, u);
}
__device__ __forceinline__ unsigned cvtpk(float lo, float hi) {
  unsigned d;
  asm("v_cvt_pk_bf16_f32 %0, %1, %2" : "=v"(d) : "v"(lo), "v"(hi));
  return d;
}
__device__ __forceinline__ void lane32swap(unsigned &x, unsigned &y) {
  asm volatile("v_permlane32_swap_b32 %0, %1" : "+v"(x), "+v"(y));
}
// async global->LDS, 16B per lane; lds dst = wave-uniform base + lane*16
__device__ __forceinline__ void gll16(const void* g, void* l) {
  __builtin_amdgcn_global_load_lds(
      (__attribute__((address_space(1))) void*)(unsigned long long)g,
      (__attribute__((address_space(3))) void*)l, 16, 0, 0);
}

// ---------------------------------------------------------------------------
// pre-pass: fp32 -> bf16 (x and the 3 qkv weights)
// ---------------------------------------------------------------------------
__global__ __launch_bounds__(256) void cvt_x(const float* __restrict__ s,
                                             unsigned short* __restrict__ d) {
  size_t i = ((size_t)blockIdx.x * 256 + threadIdx.x) * 8;
  f32x4 a = *(const f32x4*)(s + i);
  f32x4 b = *(const f32x4*)(s + i + 4);
  u16x8 o;
#pragma unroll
  for (int j = 0; j < 4; ++j) { o[j] = f2bf(a[j]); o[j + 4] = f2bf(b[j]); }
  *(u16x8*)(d + i) = o;
}

__global__ __launch_bounds__(256) void cvt_w3(const float* __restrict__ qw,
                                              const float* __restrict__ kw,
                                              const float* __restrict__ vw,
                                              unsigned short* __restrict__ dst) {
  const float* s = blockIdx.y == 0 ? qw : (blockIdx.y == 1 ? kw : vw);
  unsigned short* d = dst + (size_t)blockIdx.y * (ND * ND);
  size_t i = ((size_t)blockIdx.x * 256 + threadIdx.x) * 8;
  f32x4 a = *(const f32x4*)(s + i);
  f32x4 b = *(const f32x4*)(s + i + 4);
  u16x8 o;
#pragma unroll
  for (int j = 0; j < 4; ++j) { o[j] = f2bf(a[j]); o[j + 4] = f2bf(b[j]); }
  *(u16x8*)(d + i) = o;
}

// ---------------------------------------------------------------------------
// zero pads: q80/k80 cols 72..79 (131072 rows each); v_t rows 73..95
// threads: 262144 + 32*23*512 = 638976 = 2496 * 256
// ---------------------------------------------------------------------------
__global__ __launch_bounds__(256) void pad_zero(unsigned short* __restrict__ q80,
                                                unsigned short* __restrict__ k80,
                                                unsigned short* __restrict__ vt) {
  int i = blockIdx.x * 256 + threadIdx.x;
  u16x8 z = {};
  if (i < 131072) {
    *(u16x8*)(q80 + (size_t)i * HP + HD) = z;
  } else if (i < 262144) {
    *(u16x8*)(k80 + (size_t)(i - 131072) * HP + HD) = z;
  } else {
    int j = i - 262144;               // 0..376831
    int bh = j / 11776;               // 23*512 chunks per bh
    int r = j % 11776;
    int row = 73 + r / 512;
    int col = (r % 512) * 8;
    *(u16x8*)(vt + ((size_t)bh * VP + row) * NS + col) = z;
  }
}

// ones row: v_t[bh][72][s] = 1.0 -> PV accumulates softmax denominator free
__global__ __launch_bounds__(256) void fill_ones(unsigned short* __restrict__ vt) {
  unsigned short* p = vt + ((size_t)blockIdx.x * VP + HD) * NS;
  u16x8 v;
#pragma unroll
  for (int j = 0; j < 8; ++j) v[j] = 0x3F80;  // bf16 1.0
  for (int i = threadIdx.x; i < NS / 8; i += 256)
    *(u16x8*)(p + i * 8) = v;
}

// ---------------------------------------------------------------------------
// QKV projection v3 (m97 structure): both operands bf16 via global_load_lds.
// C[8192,1152] = xb . wb[proj]^T + bias; 128x128 tile, BK=64, LDS [128][64].
// Epilogue scatters: Q -> q80 (x QSCALE), K -> k80, V -> v_t transposed.
// ---------------------------------------------------------------------------
__global__ __launch_bounds__(256) void qkv_gemm(
    const unsigned short* __restrict__ xb, const unsigned short* __restrict__ wb,
    const float* __restrict__ qbias, const float* __restrict__ kbias,
    const float* __restrict__ vbias,
    unsigned short* __restrict__ qp, unsigned short* __restrict__ kp,
    unsigned short* __restrict__ vt)
{
  const int mb = blockIdx.x * 128;
  const int nb = blockIdx.y * 128;
  const int proj = blockIdx.z;
  const unsigned short* w = wb + (size_t)proj * (ND * ND);
  const float* bias = proj == 0 ? qbias : (proj == 1 ? kbias : vbias);

  __shared__ __align__(16) unsigned short la[128 * 64];
  __shared__ __align__(16) unsigned short lb[128 * 64];

  const int t = threadIdx.x;
  const int lane = t & 63;
  const int wid = t >> 6;
  const int mo = (wid >> 1) * 64, no = (wid & 1) * 64;
  const int l15 = lane & 15, l4 = lane >> 4;

  // gll source: wave wid, issue j covers rows wid*32+j*8 .. +7, cols (lane&7)*8
  const unsigned short* ga = xb + (size_t)(mb + wid * 32 + (lane >> 3)) * ND + (lane & 7) * 8;
  const unsigned short* gb = w  + (size_t)(nb + wid * 32 + (lane >> 3)) * ND + (lane & 7) * 8;

  f32x4 acc[4][4] = {};

  for (int kt = 0; kt < ND / 64; ++kt) {
    const int k0 = kt * 64;
    __syncthreads();
#pragma unroll
    for (int j = 0; j < 4; ++j) {
      gll16(ga + (size_t)j * 8 * ND + k0, &la[(wid * 4 + j) * 512]);
      gll16(gb + (size_t)j * 8 * ND + k0, &lb[(wid * 4 + j) * 512]);
    }
    __syncthreads();
#pragma unroll
    for (int ks = 0; ks < 2; ++ks) {
      bf16x8 af[4], bfr[4];
#pragma unroll
      for (int mt = 0; mt < 4; ++mt)
        af[mt] = asbf(*(const u16x8*)(&la[(mo + mt * 16 + l15) * 64 + ks * 32 + l4 * 8]));
#pragma unroll
      for (int nt = 0; nt < 4; ++nt)
        bfr[nt] = asbf(*(const u16x8*)(&lb[(no + nt * 16 + l15) * 64 + ks * 32 + l4 * 8]));
#pragma unroll
      for (int mt = 0; mt < 4; ++mt)
#pragma unroll
        for (int nt = 0; nt < 4; ++nt)
          acc[mt][nt] = __builtin_amdgcn_mfma_f32_16x16x32_bf16(af[mt], bfr[nt], acc[mt][nt], 0, 0, 0);
    }
  }

#pragma unroll
  for (int mt = 0; mt < 4; ++mt) {
#pragma unroll
    for (int nt = 0; nt < 4; ++nt) {
      const int n = nb + no + nt * 16 + l15;
      const float bval = bias[n];
      const int h = n / HD, hd = n % HD;
#pragma unroll
      for (int r = 0; r < 4; ++r) {
        const int m = mb + mo + mt * 16 + l4 * 4 + r;
        const int b = m >> 12, sl = m & (NS - 1);
        const int bh = b * NH + h;
        float v = acc[mt][nt][r] + bval;
        if (proj == 0)
          qp[((size_t)bh * NS + sl) * HP + hd] = f2bf(v * QSCALE);
        else if (proj == 1)
          kp[((size_t)bh * NS + sl) * HP + hd] = f2bf(v);
        else
          vt[((size_t)bh * VP + hd) * NS + sl] = f2bf(v);
      }
    }
  }
}

// ---------------------------------------------------------------------------
// Flash attention v6: 32x32x16 MFMA, 4 waves x 32 q = 128 q/block, grid 1024
// (4 blocks/CU -> independent barrier domains). K/V staged via global_load_lds
// into frag-linear LDS (22 x 1KB wave-issues/iter). In-register P (cvt_pk +
// permlane32_swap), m=0 softmax, V-ones denominator, setprio on MFMA clusters.
// ---------------------------------------------------------------------------
__global__ __launch_bounds__(256, 4) void attn_fwd(
    const unsigned short* __restrict__ qp,
    const unsigned short* __restrict__ kp,
    const unsigned short* __restrict__ vt,
    unsigned short* __restrict__ ao)
{
  const int d = blockIdx.x;            // 1024 blocks
  const int qt = (d >> 3) & 31;
  const int bh = (d & 7) + 8 * (d >> 8);
  const int b = bh >> 4, h = bh & 15;
  const int qs0 = qt * 128;

  __shared__ __align__(16) unsigned short sm[1408 * 8];  // K: chunks 0..639, V: 640..1407

  const int t = threadIdx.x;
  const int wv = t >> 6;
  const int lane = t & 63;
  const int q = lane & 31;
  const int hh = lane >> 5;

  // Q B-frags: lane holds Q[q][ks*16 + hh*8 + j]
  bf16x8 qf[5];
  {
    const unsigned short* qrow =
        qp + ((size_t)bh * NS + qs0 + wv * 32 + q) * HP + hh * 8;
#pragma unroll
    for (int ks = 0; ks < 5; ++ks)
      qf[ks] = asbf(*(const u16x8*)(qrow + ks * 16));
  }

  // staging sources: wave wv issues chunk-blocks cb = wv*5+j (j<5), waves 0,1
  // additionally cb = 20+wv. cb<10: K block (mt=cb/5, ks=cb%5); cb>=10: V
  // block f=cb-10 (hdt=f>>2, ks2=f&3).
  const unsigned short* kb0 = kp + (size_t)bh * NS * HP;
  const unsigned short* vb0 = vt + (size_t)bh * VP * NS;
  const unsigned short* gp[5];
  int stp[5];
#pragma unroll
  for (int j = 0; j < 5; ++j) {
    const int cb = wv * 5 + j;
    if (cb < 10) {
      gp[j] = kb0 + ((cb / 5) * 32 + (lane & 31)) * HP + (cb % 5) * 16 + (lane >> 5) * 8;
      stp[j] = 64 * HP;
    } else {
      const int f = cb - 10;
      gp[j] = vb0 + (size_t)((f >> 2) * 32 + (lane & 31)) * NS + (f & 3) * 16 + (lane >> 5) * 8;
      stp[j] = 64;
    }
  }
  const unsigned short* gp5 = vb0;
  if (wv < 2) {
    const int f = 10 + wv;
    gp5 = vb0 + (size_t)((f >> 2) * 32 + (lane & 31)) * NS + (f & 3) * 16 + (lane >> 5) * 8;
  }

  f32x16 o[3] = {};   // O^T: col q, row hd = hdt*32+(reg&3)+8*(reg>>2)+4*hh

  for (int it = 0; it < NS / 64; ++it) {
    __syncthreads();                    // prior iter's LDS reads complete
#pragma unroll
    for (int j = 0; j < 5; ++j) {
      gll16(gp[j], &sm[(wv * 5 + j) * 512]);
      gp[j] += stp[j];
    }
    if (wv < 2) { gll16(gp5, &sm[(20 + wv) * 512]); gp5 += 64; }
    __syncthreads();                    // drain: K/V tiles visible

#pragma unroll
    for (int mt = 0; mt < 2; ++mt) {
      // S^T tile [32k x 32q], contraction over hd 0..79
      f32x16 s = {};
      __builtin_amdgcn_s_setprio(1);
#pragma unroll
      for (int ks = 0; ks < 5; ++ks) {
        bf16x8 kf = asbf(*(const u16x8*)(&sm[((mt * 5 + ks) * 64 + lane) * 8]));
        s = __builtin_amdgcn_mfma_f32_32x32x16_bf16(kf, qf[ks], s, 0, 0, 0);
      }
      __builtin_amdgcn_s_setprio(0);
      // P = exp2(S)  (m=0 softmax)
#pragma unroll
      for (int i = 0; i < 16; ++i) s[i] = exp2f(s[i]);
      unsigned dk[8];
#pragma unroll
      for (int r2 = 0; r2 < 4; ++r2) {
        dk[2 * r2]     = cvtpk(s[4 * r2],     s[4 * r2 + 1]);
        dk[2 * r2 + 1] = cvtpk(s[4 * r2 + 2], s[4 * r2 + 3]);
      }
#pragma unroll
      for (int a = 0; a < 2; ++a) {
        unsigned x0 = dk[4 * a + 0], y0 = dk[4 * a + 2];
        unsigned x1 = dk[4 * a + 1], y1 = dk[4 * a + 3];
        lane32swap(x0, y0);
        lane32swap(x1, y1);
        u32x4 wd = {x0, x1, y0, y1};
        bf16x8 pf = __builtin_bit_cast(bf16x8, wd);
        const int ks2 = mt * 2 + a;
        __builtin_amdgcn_s_setprio(1);
#pragma unroll
        for (int hdt = 0; hdt < 3; ++hdt) {
          bf16x8 vf = asbf(*(const u16x8*)(&sm[(640 + (hdt * 4 + ks2) * 64 + lane) * 8]));
          o[hdt] = __builtin_amdgcn_mfma_f32_32x32x16_bf16(vf, pf, o[hdt], 0, 0, 0);
        }
        __builtin_amdgcn_s_setprio(0);
      }
    }
  }

  // epilogue: denom = O row 72 (hdt=2, reg 4, hh=0 lanes)
  const float l_tot = __shfl(o[2][4], q);
  const float inv = 1.0f / l_tot;
  const int srow = qs0 + wv * 32 + q;
  unsigned short* ob = ao + ((size_t)b * NS + srow) * ND + h * HD;
#pragma unroll
  for (int hdt = 0; hdt < 3; ++hdt)
#pragma unroll
    for (int r2 = 0; r2 < 4; ++r2) {
      const int hd0 = hdt * 32 + r2 * 8 + hh * 4;
      if (hd0 < HD) {
        u16x4 ov;
#pragma unroll
        for (int r0 = 0; r0 < 4; ++r0) ov[r0] = f2bf(o[hdt][r2 * 4 + r0] * inv);
        *(u16x4*)(ob + hd0) = ov;
      }
    }
}

// ---------------------------------------------------------------------------
// O projection v3: A (attn_o bf16) via global_load_lds; B (o_w fp32) cvt-staged.
// out[8192,1152] fp32 = attn_o . o_w^T + o_b
// ---------------------------------------------------------------------------
__global__ __launch_bounds__(256) void oproj_gemm(
    const unsigned short* __restrict__ a,
    const float* __restrict__ w, const float* __restrict__ bias,
    float* __restrict__ out)
{
  const int mb = blockIdx.x * 128;
  const int nb = blockIdx.y * 128;

  __shared__ __align__(16) unsigned short la[128 * 64];
  __shared__ __align__(16) unsigned short lb[128 * 64];

  const int t = threadIdx.x;
  const int lane = t & 63;
  const int wid = t >> 6;
  const int mo = (wid >> 1) * 64, no = (wid & 1) * 64;
  const int l15 = lane & 15, l4 = lane >> 4;

  const unsigned short* ga = a + (size_t)(mb + wid * 32 + (lane >> 3)) * ND + (lane & 7) * 8;

  f32x4 acc[4][4] = {};

  for (int kt = 0; kt < ND / 64; ++kt) {
    const int k0 = kt * 64;
    __syncthreads();
#pragma unroll
    for (int j = 0; j < 4; ++j)
      gll16(ga + (size_t)j * 8 * ND + k0, &la[(wid * 4 + j) * 512]);
#pragma unroll
    for (int i = 0; i < 8; ++i) {
      int c = t + i * 256;
      int row = c >> 4, c4 = c & 15;
      f32x4 b4 = *(const f32x4*)(w + (size_t)(nb + row) * ND + k0 + c4 * 4);
      u16x4 ub;
#pragma unroll
      for (int j = 0; j < 4; ++j) ub[j] = f2bf(b4[j]);
      *(u16x4*)(&lb[row * 64 + c4 * 4]) = ub;
    }
    __syncthreads();
#pragma unroll
    for (int ks = 0; ks < 2; ++ks) {
      bf16x8 af[4], bfr[4];
#pragma unroll
      for (int mt = 0; mt < 4; ++mt)
        af[mt] = asbf(*(const u16x8*)(&la[(mo + mt * 16 + l15) * 64 + ks * 32 + l4 * 8]));
#pragma unroll
      for (int nt = 0; nt < 4; ++nt)
        bfr[nt] = asbf(*(const u16x8*)(&lb[(no + nt * 16 + l15) * 64 + ks * 32 + l4 * 8]));
#pragma unroll
      for (int mt = 0; mt < 4; ++mt)
#pragma unroll
        for (int nt = 0; nt < 4; ++nt)
          acc[mt][nt] = __builtin_amdgcn_mfma_f32_16x16x32_bf16(af[mt], bfr[nt], acc[mt][nt], 0, 0, 0);
    }
  }

#pragma unroll
  for (int mt = 0; mt < 4; ++mt)
#pragma unroll
    for (int nt = 0; nt < 4; ++nt) {
      const int n = nb + no + nt * 16 + l15;
      const float bval = bias[n];
#pragma unroll
      for (int r = 0; r < 4; ++r) {
        const int m = mb + mo + mt * 16 + l4 * 4 + r;
        out[(size_t)m * ND + n] = acc[mt][nt][r] + bval;
      }
    }
}

// ---------------------------------------------------------------------------
extern "C" void kernel_launch(void* const* d_in, const int* in_sizes, int n_in,
                              void* d_out, int out_size, void* d_ws, size_t ws_size,
                              hipStream_t stream) {
  const float* x  = (const float*)d_in[0];
  const float* qw = (const float*)d_in[1];
  const float* qb = (const float*)d_in[2];
  const float* kw = (const float*)d_in[3];
  const float* kb = (const float*)d_in[4];
  const float* vw = (const float*)d_in[5];
  const float* vb = (const float*)d_in[6];
  const float* ow = (const float*)d_in[7];
  const float* ob = (const float*)d_in[8];
  float* out = (float*)d_out;

  // ws layout (bytes), total 93,945,856 (< proven 94,371,840 capacity):
  //   q80   [2,16,4096,80] bf16 @ 0           (20,971,520)
  //   k80   [2,16,4096,80] bf16 @ 20,971,520  (20,971,520)
  //   v_t   [2,16,96,4096] bf16 @ 41,943,040  (25,165,824)
  //   xb/ao [8192,1152]    bf16 @ 67,108,864  (18,874,368)  xb dies before ao born
  //   wqkv  3x[1152,1152]  bf16 @ 85,983,232  ( 7,962,624)
  char* ws = (char*)d_ws;
  unsigned short* q80  = (unsigned short*)(ws);
  unsigned short* k80  = (unsigned short*)(ws + 20971520);
  unsigned short* v_t  = (unsigned short*)(ws + 41943040);
  unsigned short* xb   = (unsigned short*)(ws + 67108864);  // also attn_o
  unsigned short* wb   = (unsigned short*)(ws + 85983232);

  pad_zero<<<dim3(2496), dim3(256), 0, stream>>>(q80, k80, v_t);
  fill_ones<<<dim3(32), dim3(256), 0, stream>>>(v_t);
  cvt_x<<<dim3(4608), dim3(256), 0, stream>>>(x, xb);
  cvt_w3<<<dim3(648, 3), dim3(256), 0, stream>>>(qw, kw, vw, wb);
  qkv_gemm<<<dim3(64, 9, 3), dim3(256), 0, stream>>>(xb, wb, qb, kb, vb,
                                                     q80, k80, v_t);
  attn_fwd<<<dim3(1024), dim3(256), 0, stream>>>(q80, k80, v_t, xb /*= attn_o*/);
  oproj_gemm<<<dim3(64, 9), dim3(256), 0, stream>>>(xb /*attn_o*/, ow, ob, out);
}

// Round 9
// 437.999 us; speedup vs baseline: 1.0181x; 1.0181x over previous
//
#include <hip/hip_runtime.h>

#define NB 2
#define NS 4096
#define ND 1152
#define NH 16
#define HD 72
#define HP 80            // q/k padded head dim (cols 72..79 zero)
#define VP 96            // v_t rows (72=ones, 73..95 zero)
// 72^-0.5 * log2(e): attention computed in exp2 domain
#define QSCALE (0.11785113019775793f * 1.4426950408889634f)

typedef float f32x4 __attribute__((ext_vector_type(4)));
typedef float f32x16 __attribute__((ext_vector_type(16)));
typedef __bf16 bf16x8 __attribute__((ext_vector_type(8)));
typedef unsigned short u16x8 __attribute__((ext_vector_type(8)));
typedef unsigned short u16x4 __attribute__((ext_vector_type(4)));
typedef unsigned int u32x4 __attribute__((ext_vector_type(4)));

__device__ __forceinline__ unsigned short f2bf(float f) {
  return __builtin_bit_cast(unsigned short, (__bf16)f);  // v_cvt RNE
}
__device__ __forceinline__ bf16x8 asbf(u16x8 u) {
  return __builtin_bit_cast(bf16x8, u);
}
__device__ __forceinline__ unsigned cvtpk(float lo, float hi) {
  unsigned d;
  asm("v_cvt_pk_bf16_f32 %0, %1, %2" : "=v"(d) : "v"(lo), "v"(hi));
  return d;
}
__device__ __forceinline__ void lane32swap(unsigned &x, unsigned &y) {
  asm volatile("v_permlane32_swap_b32 %0, %1" : "+v"(x), "+v"(y));
}
// async global->LDS, 16B per lane; lds dst = wave-uniform base + lane*16
__device__ __forceinline__ void gll16(const void* g, void* l) {
  __builtin_amdgcn_global_load_lds(
      (__attribute__((address_space(1))) void*)(unsigned long long)g,
      (__attribute__((address_space(3))) void*)l, 16, 0, 0);
}

// ---------------------------------------------------------------------------
// pre-pass: fp32 -> bf16 converters
// ---------------------------------------------------------------------------
__global__ __launch_bounds__(256) void cvt_x(const float* __restrict__ s,
                                             unsigned short* __restrict__ d) {
  size_t i = ((size_t)blockIdx.x * 256 + threadIdx.x) * 8;
  f32x4 a = *(const f32x4*)(s + i);
  f32x4 b = *(const f32x4*)(s + i + 4);
  u16x8 o;
#pragma unroll
  for (int j = 0; j < 4; ++j) { o[j] = f2bf(a[j]); o[j + 4] = f2bf(b[j]); }
  *(u16x8*)(d + i) = o;
}

__global__ __launch_bounds__(256) void cvt_w3(const float* __restrict__ qw,
                                              const float* __restrict__ kw,
                                              const float* __restrict__ vw,
                                              unsigned short* __restrict__ dst) {
  const float* s = blockIdx.y == 0 ? qw : (blockIdx.y == 1 ? kw : vw);
  unsigned short* d = dst + (size_t)blockIdx.y * (ND * ND);
  size_t i = ((size_t)blockIdx.x * 256 + threadIdx.x) * 8;
  f32x4 a = *(const f32x4*)(s + i);
  f32x4 b = *(const f32x4*)(s + i + 4);
  u16x8 o;
#pragma unroll
  for (int j = 0; j < 4; ++j) { o[j] = f2bf(a[j]); o[j + 4] = f2bf(b[j]); }
  *(u16x8*)(d + i) = o;
}

// ---------------------------------------------------------------------------
// zero pads: q80/k80 cols 72..79 (131072 rows each); v_t rows 73..95
// ---------------------------------------------------------------------------
__global__ __launch_bounds__(256) void pad_zero(unsigned short* __restrict__ q80,
                                                unsigned short* __restrict__ k80,
                                                unsigned short* __restrict__ vt) {
  int i = blockIdx.x * 256 + threadIdx.x;
  u16x8 z = {};
  if (i < 131072) {
    *(u16x8*)(q80 + (size_t)i * HP + HD) = z;
  } else if (i < 262144) {
    *(u16x8*)(k80 + (size_t)(i - 131072) * HP + HD) = z;
  } else {
    int j = i - 262144;               // 0..376831
    int bh = j / 11776;               // 23*512 chunks per bh
    int r = j % 11776;
    int row = 73 + r / 512;
    int col = (r % 512) * 8;
    *(u16x8*)(vt + ((size_t)bh * VP + row) * NS + col) = z;
  }
}

// ones row: v_t[bh][72][s] = 1.0 -> PV accumulates softmax denominator free
__global__ __launch_bounds__(256) void fill_ones(unsigned short* __restrict__ vt) {
  unsigned short* p = vt + ((size_t)blockIdx.x * VP + HD) * NS;
  u16x8 v;
#pragma unroll
  for (int j = 0; j < 8; ++j) v[j] = 0x3F80;  // bf16 1.0
  for (int i = threadIdx.x; i < NS / 8; i += 256)
    *(u16x8*)(p + i * 8) = v;
}

// ---------------------------------------------------------------------------
// QKV projection: both operands bf16 via global_load_lds (m97 structure).
// C[8192,1152] = xb . wb[proj]^T + bias; 128x128 tile, BK=64.
// proj 0/1: normal orientation -> q80/k80 (rows = s, coalesced along hd).
// proj 2: MFMA operands SWAPPED -> acc holds C^T (col=m=s) so the v_t
//         epilogue stores are contiguous along s (32B/16-lane segments).
// ---------------------------------------------------------------------------
__global__ __launch_bounds__(256) void qkv_gemm(
    const unsigned short* __restrict__ xb, const unsigned short* __restrict__ wb,
    const float* __restrict__ qbias, const float* __restrict__ kbias,
    const float* __restrict__ vbias,
    unsigned short* __restrict__ qp, unsigned short* __restrict__ kp,
    unsigned short* __restrict__ vt)
{
  const int mb = blockIdx.x * 128;
  const int nb = blockIdx.y * 128;
  const int proj = blockIdx.z;
  const unsigned short* w = wb + (size_t)proj * (ND * ND);
  const float* bias = proj == 0 ? qbias : (proj == 1 ? kbias : vbias);

  __shared__ __align__(16) unsigned short la[128 * 64];
  __shared__ __align__(16) unsigned short lb[128 * 64];

  const int t = threadIdx.x;
  const int lane = t & 63;
  const int wid = t >> 6;
  const int mo = (wid >> 1) * 64, no = (wid & 1) * 64;
  const int l15 = lane & 15, l4 = lane >> 4;

  const unsigned short* ga = xb + (size_t)(mb + wid * 32 + (lane >> 3)) * ND + (lane & 7) * 8;
  const unsigned short* gb = w  + (size_t)(nb + wid * 32 + (lane >> 3)) * ND + (lane & 7) * 8;

  f32x4 acc[4][4] = {};

  for (int kt = 0; kt < ND / 64; ++kt) {
    const int k0 = kt * 64;
    __syncthreads();
#pragma unroll
    for (int j = 0; j < 4; ++j) {
      gll16(ga + (size_t)j * 8 * ND + k0, &la[(wid * 4 + j) * 512]);
      gll16(gb + (size_t)j * 8 * ND + k0, &lb[(wid * 4 + j) * 512]);
    }
    __syncthreads();
#pragma unroll
    for (int ks = 0; ks < 2; ++ks) {
      bf16x8 af[4], bfr[4];
#pragma unroll
      for (int mt = 0; mt < 4; ++mt)
        af[mt] = asbf(*(const u16x8*)(&la[(mo + mt * 16 + l15) * 64 + ks * 32 + l4 * 8]));
#pragma unroll
      for (int nt = 0; nt < 4; ++nt)
        bfr[nt] = asbf(*(const u16x8*)(&lb[(no + nt * 16 + l15) * 64 + ks * 32 + l4 * 8]));
      if (proj == 2) {
#pragma unroll
        for (int mt = 0; mt < 4; ++mt)
#pragma unroll
          for (int nt = 0; nt < 4; ++nt)
            acc[mt][nt] = __builtin_amdgcn_mfma_f32_16x16x32_bf16(bfr[nt], af[mt], acc[mt][nt], 0, 0, 0);
      } else {
#pragma unroll
        for (int mt = 0; mt < 4; ++mt)
#pragma unroll
          for (int nt = 0; nt < 4; ++nt)
            acc[mt][nt] = __builtin_amdgcn_mfma_f32_16x16x32_bf16(af[mt], bfr[nt], acc[mt][nt], 0, 0, 0);
      }
    }
  }

  if (proj == 2) {
    // acc = C^T: col(l15)=m, row(l4*4+r)=n
#pragma unroll
    for (int mt = 0; mt < 4; ++mt) {
      const int m = mb + mo + mt * 16 + l15;
      const int b = m >> 12, sl = m & (NS - 1);
#pragma unroll
      for (int nt = 0; nt < 4; ++nt) {
#pragma unroll
        for (int r = 0; r < 4; ++r) {
          const int n = nb + no + nt * 16 + l4 * 4 + r;
          const int h = n / HD, hd = n % HD;
          vt[(((size_t)(b * NH + h)) * VP + hd) * NS + sl] =
              f2bf(acc[mt][nt][r] + bias[n]);
        }
      }
    }
  } else {
#pragma unroll
    for (int mt = 0; mt < 4; ++mt) {
#pragma unroll
      for (int nt = 0; nt < 4; ++nt) {
        const int n = nb + no + nt * 16 + l15;
        const float bval = bias[n];
        const int h = n / HD, hd = n % HD;
#pragma unroll
        for (int r = 0; r < 4; ++r) {
          const int m = mb + mo + mt * 16 + l4 * 4 + r;
          const int b = m >> 12, sl = m & (NS - 1);
          const int bh = b * NH + h;
          float v = acc[mt][nt][r] + bval;
          if (proj == 0)
            qp[((size_t)bh * NS + sl) * HP + hd] = f2bf(v * QSCALE);
          else
            kp[((size_t)bh * NS + sl) * HP + hd] = f2bf(v);
        }
      }
    }
  }
}

// ---------------------------------------------------------------------------
// Flash attention v8: 32x32x16 MFMA, 8 waves x 32 q = 256 q/block, grid 512.
// TRUE 2-phase pipeline: double-buffered LDS, ONE barrier per iter; gll for
// tile t+1 issued BEFORE computing tile t, so the compiler's vmcnt(0)-at-
// barrier lands after the compute phase (latency hidden by construction).
// In-register P (cvt_pk + permlane32_swap), m=0 softmax, V-ones denominator,
// setprio on MFMA clusters, XCD remap.
// ---------------------------------------------------------------------------
__global__ __launch_bounds__(512, 4) void attn_fwd(
    const unsigned short* __restrict__ qp,
    const unsigned short* __restrict__ kp,
    const unsigned short* __restrict__ vt,
    unsigned short* __restrict__ ao)
{
  const int d = blockIdx.x;            // 512 blocks, 2 per CU
  const int qt = (d >> 3) & 15;
  const int bh = (d & 7) + 8 * (d >> 7);
  const int b = bh >> 4, h = bh & 15;
  const int qs0 = qt * 256;

  // two buffers of 1408 16B-chunks: K chunks 0..639, V chunks 640..1407
  __shared__ __align__(16) unsigned short sm[2 * 1408 * 8];

  const int t = threadIdx.x;
  const int wv = t >> 6;
  const int lane = t & 63;
  const int q = lane & 31;
  const int hh = lane >> 5;

  // Q B-frags: lane holds Q[q][ks*16 + hh*8 + j]
  bf16x8 qf[5];
  {
    const unsigned short* qrow =
        qp + ((size_t)bh * NS + qs0 + wv * 32 + q) * HP + hh * 8;
#pragma unroll
    for (int ks = 0; ks < 5; ++ks)
      qf[ks] = asbf(*(const u16x8*)(qrow + ks * 16));
  }

  // staging: 22 chunk-groups of 64; wave wv handles g = wv, wv+8, wv+16(wv<6).
  // g<10: K group (mt=g/5, ks=g%5); g>=10: V group f=g-10 (hdt=f>>2, ks2=f&3).
  const unsigned short* kb0 = kp + (size_t)bh * NS * HP;
  const unsigned short* vb0 = vt + (size_t)bh * VP * NS;
  const unsigned short* gp[3];
  int stp[3], goff[3];
  const bool has2 = wv < 6;
#pragma unroll
  for (int j = 0; j < 3; ++j) {
    int g = wv + 8 * j;
    if (g > 21) g = 21;                // inert clamp for waves 6,7 j=2
    if (g < 10) {
      gp[j] = kb0 + ((g / 5) * 32 + (lane & 31)) * HP + (g % 5) * 16 + (lane >> 5) * 8;
      stp[j] = 64 * HP;
    } else {
      const int f = g - 10;
      gp[j] = vb0 + (size_t)((f >> 2) * 32 + (lane & 31)) * NS + (f & 3) * 16 + (lane >> 5) * 8;
      stp[j] = 64;
    }
    goff[j] = g * 512;                 // u16 elems: g*64 chunks * 8
  }

  f32x16 o[3] = {};   // O^T: col q, row hd = hdt*32+(reg&3)+8*(reg>>2)+4*hh

  // prologue: stage tile 0 into buffer 0
  {
    unsigned short* buf = sm;
    gll16(gp[0], buf + goff[0]); gp[0] += stp[0];
    gll16(gp[1], buf + goff[1]); gp[1] += stp[1];
    if (has2) { gll16(gp[2], buf + goff[2]); gp[2] += stp[2]; }
  }
  __syncthreads();

  for (int it = 0; it < NS / 64; ++it) {
    unsigned short* cur = sm + (it & 1) * 11264;
    unsigned short* nxt = sm + ((it + 1) & 1) * 11264;
    if (it < NS / 64 - 1) {            // issue next tile; drains at the barrier
      gll16(gp[0], nxt + goff[0]); gp[0] += stp[0];
      gll16(gp[1], nxt + goff[1]); gp[1] += stp[1];
      if (has2) { gll16(gp[2], nxt + goff[2]); gp[2] += stp[2]; }
    }

#pragma unroll
    for (int mt = 0; mt < 2; ++mt) {
      // S^T tile [32k x 32q], contraction over hd 0..79
      f32x16 s = {};
      __builtin_amdgcn_s_setprio(1);
#pragma unroll
      for (int ks = 0; ks < 5; ++ks) {
        bf16x8 kf = asbf(*(const u16x8*)(&cur[((mt * 5 + ks) * 64 + lane) * 8]));
        s = __builtin_amdgcn_mfma_f32_32x32x16_bf16(kf, qf[ks], s, 0, 0, 0);
      }
      __builtin_amdgcn_s_setprio(0);
      // P = exp2(S)  (m=0 softmax)
#pragma unroll
      for (int i = 0; i < 16; ++i) s[i] = exp2f(s[i]);
      unsigned dk[8];
#pragma unroll
      for (int r2 = 0; r2 < 4; ++r2) {
        dk[2 * r2]     = cvtpk(s[4 * r2],     s[4 * r2 + 1]);
        dk[2 * r2 + 1] = cvtpk(s[4 * r2 + 2], s[4 * r2 + 3]);
      }
#pragma unroll
      for (int a = 0; a < 2; ++a) {
        unsigned x0 = dk[4 * a + 0], y0 = dk[4 * a + 2];
        unsigned x1 = dk[4 * a + 1], y1 = dk[4 * a + 3];
        lane32swap(x0, y0);
        lane32swap(x1, y1);
        u32x4 wd = {x0, x1, y0, y1};
        bf16x8 pf = __builtin_bit_cast(bf16x8, wd);
        const int ks2 = mt * 2 + a;
        __builtin_amdgcn_s_setprio(1);
#pragma unroll
        for (int hdt = 0; hdt < 3; ++hdt) {
          bf16x8 vf = asbf(*(const u16x8*)(&cur[(640 + (hdt * 4 + ks2) * 64 + lane) * 8]));
          o[hdt] = __builtin_amdgcn_mfma_f32_32x32x16_bf16(vf, pf, o[hdt], 0, 0, 0);
        }
        __builtin_amdgcn_s_setprio(0);
      }
    }
    __syncthreads();                   // drains gll(t+1); all waves done w/ cur
  }

  // epilogue: denom = O row 72 (hdt=2, reg 4, hh=0 lanes)
  const float l_tot = __shfl(o[2][4], q);
  const float inv = 1.0f / l_tot;
  const int srow = qs0 + wv * 32 + q;
  unsigned short* ob = ao + ((size_t)b * NS + srow) * ND + h * HD;
#pragma unroll
  for (int hdt = 0; hdt < 3; ++hdt)
#pragma unroll
    for (int r2 = 0; r2 < 4; ++r2) {
      const int hd0 = hdt * 32 + r2 * 8 + hh * 4;
      if (hd0 < HD) {
        u16x4 ov;
#pragma unroll
        for (int r0 = 0; r0 < 4; ++r0) ov[r0] = f2bf(o[hdt][r2 * 4 + r0] * inv);
        *(u16x4*)(ob + hd0) = ov;
      }
    }
}

// ---------------------------------------------------------------------------
// O projection: both operands bf16 via global_load_lds.
// out[8192,1152] fp32 = attn_o . o_w^T + o_b
// ---------------------------------------------------------------------------
__global__ __launch_bounds__(256) void oproj_gemm(
    const unsigned short* __restrict__ a,
    const unsigned short* __restrict__ wbf, const float* __restrict__ bias,
    float* __restrict__ out)
{
  const int mb = blockIdx.x * 128;
  const int nb = blockIdx.y * 128;

  __shared__ __align__(16) unsigned short la[128 * 64];
  __shared__ __align__(16) unsigned short lb[128 * 64];

  const int t = threadIdx.x;
  const int lane = t & 63;
  const int wid = t >> 6;
  const int mo = (wid >> 1) * 64, no = (wid & 1) * 64;
  const int l15 = lane & 15, l4 = lane >> 4;

  const unsigned short* ga = a   + (size_t)(mb + wid * 32 + (lane >> 3)) * ND + (lane & 7) * 8;
  const unsigned short* gb = wbf + (size_t)(nb + wid * 32 + (lane >> 3)) * ND + (lane & 7) * 8;

  f32x4 acc[4][4] = {};

  for (int kt = 0; kt < ND / 64; ++kt) {
    const int k0 = kt * 64;
    __syncthreads();
#pragma unroll
    for (int j = 0; j < 4; ++j) {
      gll16(ga + (size_t)j * 8 * ND + k0, &la[(wid * 4 + j) * 512]);
      gll16(gb + (size_t)j * 8 * ND + k0, &lb[(wid * 4 + j) * 512]);
    }
    __syncthreads();
#pragma unroll
    for (int ks = 0; ks < 2; ++ks) {
      bf16x8 af[4], bfr[4];
#pragma unroll
      for (int mt = 0; mt < 4; ++mt)
        af[mt] = asbf(*(const u16x8*)(&la[(mo + mt * 16 + l15) * 64 + ks * 32 + l4 * 8]));
#pragma unroll
      for (int nt = 0; nt < 4; ++nt)
        bfr[nt] = asbf(*(const u16x8*)(&lb[(no + nt * 16 + l15) * 64 + ks * 32 + l4 * 8]));
#pragma unroll
      for (int mt = 0; mt < 4; ++mt)
#pragma unroll
        for (int nt = 0; nt < 4; ++nt)
          acc[mt][nt] = __builtin_amdgcn_mfma_f32_16x16x32_bf16(af[mt], bfr[nt], acc[mt][nt], 0, 0, 0);
    }
  }

#pragma unroll
  for (int mt = 0; mt < 4; ++mt)
#pragma unroll
    for (int nt = 0; nt < 4; ++nt) {
      const int n = nb + no + nt * 16 + l15;
      const float bval = bias[n];
#pragma unroll
      for (int r = 0; r < 4; ++r) {
        const int m = mb + mo + mt * 16 + l4 * 4 + r;
        out[(size_t)m * ND + n] = acc[mt][nt][r] + bval;
      }
    }
}

// ---------------------------------------------------------------------------
extern "C" void kernel_launch(void* const* d_in, const int* in_sizes, int n_in,
                              void* d_out, int out_size, void* d_ws, size_t ws_size,
                              hipStream_t stream) {
  const float* x  = (const float*)d_in[0];
  const float* qw = (const float*)d_in[1];
  const float* qb = (const float*)d_in[2];
  const float* kw = (const float*)d_in[3];
  const float* kb = (const float*)d_in[4];
  const float* vw = (const float*)d_in[5];
  const float* vb = (const float*)d_in[6];
  const float* ow = (const float*)d_in[7];
  const float* ob = (const float*)d_in[8];
  float* out = (float*)d_out;

  // ws layout (bytes), total 93,945,856:
  //   q80   [2,16,4096,80] bf16 @ 0           (20,971,520)
  //   k80   [2,16,4096,80] bf16 @ 20,971,520  (20,971,520)
  //   v_t   [2,16,96,4096] bf16 @ 41,943,040  (25,165,824)
  //   xb/ao [8192,1152]    bf16 @ 67,108,864  (18,874,368)  xb dies before ao born
  //   wqkv  3x[1152,1152]  bf16 @ 85,983,232  ( 7,962,624)  -> ow_bf16 after qkv
  char* ws = (char*)d_ws;
  unsigned short* q80  = (unsigned short*)(ws);
  unsigned short* k80  = (unsigned short*)(ws + 20971520);
  unsigned short* v_t  = (unsigned short*)(ws + 41943040);
  unsigned short* xb   = (unsigned short*)(ws + 67108864);  // also attn_o
  unsigned short* wb   = (unsigned short*)(ws + 85983232);  // wqkv, then ow_bf16

  pad_zero<<<dim3(2496), dim3(256), 0, stream>>>(q80, k80, v_t);
  fill_ones<<<dim3(32), dim3(256), 0, stream>>>(v_t);
  cvt_x<<<dim3(4608), dim3(256), 0, stream>>>(x, xb);
  cvt_w3<<<dim3(648, 3), dim3(256), 0, stream>>>(qw, kw, vw, wb);
  qkv_gemm<<<dim3(64, 9, 3), dim3(256), 0, stream>>>(xb, wb, qb, kb, vb,
                                                     q80, k80, v_t);
  cvt_x<<<dim3(648), dim3(256), 0, stream>>>(ow, wb);  // wqkv dead; reuse for o_w
  attn_fwd<<<dim3(512), dim3(512), 0, stream>>>(q80, k80, v_t, xb /*= attn_o*/);
  oproj_gemm<<<dim3(64, 9), dim3(256), 0, stream>>>(xb /*attn_o*/, wb, ob, out);
}